// Round 2
// baseline (462.890 us; speedup 1.0000x reference)
//
#include <hip/hip_runtime.h>
#include <hip/hip_bf16.h>
#include <stdint.h>

// Problem constants: B=32, T=256, M=2048, C=F=256, K=3 (pad 1), NB=256
#define DUR_OFF 16777216
#define PIT_OFF 16785408
#define ENE_OFF 16850944
#define MEL_OFF 16916480

typedef __attribute__((ext_vector_type(8))) short short8;
typedef __attribute__((ext_vector_type(4))) float f32x4;

__device__ __forceinline__ void async16(const void* g, void* l) {
  __builtin_amdgcn_global_load_lds((__attribute__((address_space(1))) void*)g,
                                   (__attribute__((address_space(3))) void*)l, 16, 0, 0);
}

__device__ __forceinline__ unsigned short bfu(float f) {
  __hip_bfloat16 h = __float2bfloat16(f);
  return __builtin_bit_cast(unsigned short, h);
}
__device__ __forceinline__ float f_from_bf(unsigned short u) {
  return __builtin_bit_cast(float, (unsigned)u << 16);
}

// Zero the two pad rows (t=-1, t=L) of all four padded [B][L+2][256] bf16 buffers.
__global__ void zero2_kernel(__hip_bfloat16* __restrict__ xb, __hip_bfloat16* __restrict__ h1,
                             __hip_bfloat16* __restrict__ M1, __hip_bfloat16* __restrict__ M2) {
  int buf = blockIdx.x >> 6, sub = blockIdx.x & 63;
  int b = sub >> 1, top = sub & 1;
  __hip_bfloat16* p; int L;
  if (buf == 0) { p = xb; L = 256; }
  else if (buf == 1) { p = h1; L = 256; }
  else if (buf == 2) { p = M1; L = 2048; }
  else { p = M2; L = 2048; }
  size_t row = (size_t)b * (L + 2) + (top ? (L + 1) : 0);
  p[row * 256 + threadIdx.x] = __float2bfloat16(0.0f);
}

// Pack all 6 conv weights [F=256][C=256][3] f32 -> wp[wsel][f][k*256+c] bf16
__global__ void packall_kernel(const float* __restrict__ w0, const float* __restrict__ w1,
                               const float* __restrict__ w2, const float* __restrict__ w3,
                               const float* __restrict__ w4, const float* __restrict__ w5,
                               __hip_bfloat16* __restrict__ wpbase) {
  int wsel = blockIdx.x >> 8, f = blockIdx.x & 255, c = threadIdx.x;
  const float* w = wsel == 0 ? w0 : wsel == 1 ? w1 : wsel == 2 ? w2
                 : wsel == 3 ? w3 : wsel == 4 ? w4 : w5;
  __hip_bfloat16* wp = wpbase + (size_t)wsel * 196608;
  const float* src = w + ((size_t)f * 256 + c) * 3;
#pragma unroll
  for (int k = 0; k < 3; ++k)
    wp[(size_t)f * 768 + k * 256 + c] = __float2bfloat16(src[k]);
}

// x [32][256][256] f32 -> xb [32][258][256] bf16 (row t -> padded row t+1)
__global__ void cvt_pad_kernel(const float* __restrict__ x, __hip_bfloat16* __restrict__ xb) {
  int idx = blockIdx.x * 256 + threadIdx.x;
  float4 v = ((const float4*)x)[idx];
  int c4 = idx & 63;
  int rowi = idx >> 6;
  int b = rowi >> 8, t = rowi & 255;
  ushort4 o;
  o.x = bfu(v.x); o.y = bfu(v.y); o.z = bfu(v.z); o.w = bfu(v.w);
  ((ushort4*)(xb + ((size_t)b * 258 + t + 1) * 256))[c4] = o;
}

// Length regulate (in-block cumsum of true_duration) -> bf16 padded M1; chunk0 writes mel_len.
__global__ void gather_kernel(const float* __restrict__ x, const int* __restrict__ dur,
                              __hip_bfloat16* __restrict__ outB, float* __restrict__ mel) {
  __shared__ int scs[256];
  __shared__ int sidx[64];
  __shared__ int sval[64];
  int bch = blockIdx.x >> 5;
  int m0 = (blockIdx.x & 31) << 6;
  int tid = threadIdx.x;
  scs[tid] = dur[bch * 256 + tid];
  __syncthreads();
  for (int off = 1; off < 256; off <<= 1) {
    int add = (tid >= off) ? scs[tid - off] : 0;
    __syncthreads();
    scs[tid] += add;
    __syncthreads();
  }
  int total = scs[255];
  if (tid == 0 && (blockIdx.x & 31) == 0)
    mel[bch] = (float)(total < 2048 ? total : 2048);
  if (tid < 64) {
    int m = m0 + tid;
    int lo = 0, hi = 256;
    while (lo < hi) { int mid = (lo + hi) >> 1; if (scs[mid] <= m) lo = mid + 1; else hi = mid; }
    sidx[tid] = lo < 255 ? lo : 255;
    sval[tid] = (m < total);
  }
  __syncthreads();
  int lane = tid & 63, rs = tid >> 6;
  for (int r = rs; r < 64; r += 4) {
    float4 v = make_float4(0.f, 0.f, 0.f, 0.f);
    if (sval[r]) v = ((const float4*)(x + ((size_t)bch * 256 + sidx[r]) * 256))[lane];
    ushort4 o;
    o.x = bfu(v.x); o.y = bfu(v.y); o.z = bfu(v.z); o.w = bfu(v.w);
    ((ushort4*)(outB + ((size_t)bch * 2050 + m0 + r + 1) * 256))[lane] = o;
  }
}

// Fused double embedding add: M2 = bf16(M1 + pemb[idx_p]); out = (M1 + pemb) + eemb[idx_e] (f32)
__global__ void addemb_kernel(const float* __restrict__ tp, const float* __restrict__ te,
                              const float* __restrict__ pq, const float* __restrict__ eq,
                              const float* __restrict__ pemb, const float* __restrict__ eemb,
                              const __hip_bfloat16* __restrict__ M1, __hip_bfloat16* __restrict__ M2,
                              float* __restrict__ out) {
  __shared__ float sp[255], se[255];
  __shared__ int sip[64], sie[64];
  int bch = blockIdx.x >> 5;
  int m0 = (blockIdx.x & 31) << 6;
  int tid = threadIdx.x;
  if (tid < 255) { sp[tid] = pq[tid]; se[tid] = eq[tid]; }
  __syncthreads();
  if (tid < 64) {
    float xv = tp[bch * 2048 + m0 + tid];
    int lo = 0, hi = 255;
    while (lo < hi) { int mid = (lo + hi) >> 1; if (sp[mid] <= xv) lo = mid + 1; else hi = mid; }
    sip[tid] = lo;
    float ev = te[bch * 2048 + m0 + tid];
    lo = 0; hi = 255;
    while (lo < hi) { int mid = (lo + hi) >> 1; if (se[mid] <= ev) lo = mid + 1; else hi = mid; }
    sie[tid] = lo;
  }
  __syncthreads();
  int lane = tid & 63, rs = tid >> 6;
  for (int r = rs; r < 64; r += 4) {
    ushort4 mv = ((const ushort4*)(M1 + ((size_t)bch * 2050 + m0 + r + 1) * 256))[lane];
    float4 ep = ((const float4*)(pemb + (size_t)sip[r] * 256))[lane];
    float4 ee = ((const float4*)(eemb + (size_t)sie[r] * 256))[lane];
    float4 v;
    v.x = f_from_bf(mv.x) + ep.x; v.y = f_from_bf(mv.y) + ep.y;
    v.z = f_from_bf(mv.z) + ep.z; v.w = f_from_bf(mv.w) + ep.w;
    ushort4 o;
    o.x = bfu(v.x); o.y = bfu(v.y); o.z = bfu(v.z); o.w = bfu(v.w);
    ((ushort4*)(M2 + ((size_t)bch * 2050 + m0 + r + 1) * 256))[lane] = o;
    float4 w;
    w.x = v.x + ee.x; w.y = v.y + ee.y; w.z = v.z + ee.z; w.w = v.w + ee.w;
    ((float4*)(out + ((size_t)bch * 2048 + m0 + r) * 256))[lane] = w;
  }
}

// Fused conv1d(K=3,'same') + bias + ReLU + LayerNorm GEMM, 64x256 tile per block.
// A tile (66 padded rows x 256 ch, 33 KB) staged ONCE via global_load_lds with
// XOR-swizzled source (swz(a) = a ^ (((a>>9)&7)<<4), involution); ONE barrier; then
// 24 K-slices of {4 swizzled ds_read_b128 (A) + 4 direct global->reg loads (B, L2-resident
// weights, immediate offsets) + 16 MFMA} with no further barriers.
// EPI==0: store LN result bf16 into padded Hout. EPI==1: fold Linear(F->1)+ReLU -> Sout.
template <int EPI>
__global__ __launch_bounds__(256, 3)
void pred_gemm(const __hip_bfloat16* __restrict__ Ap, const __hip_bfloat16* __restrict__ Wp,
               const float* __restrict__ bias, const float* __restrict__ gamma,
               const float* __restrict__ beta, const float* __restrict__ wl,
               const float* __restrict__ blp, __hip_bfloat16* __restrict__ Hout,
               float* __restrict__ Sout, int L) {
  __shared__ char lA[33792];      // 66 rows x 512 B (swizzled)
  __shared__ float lred[64 * 8];
  __shared__ float lstat[64 * 2];

  const int tid = threadIdx.x;
  const int wid = tid >> 6;
  const int lane = tid & 63;
  const int wn = wid;             // wave -> 64-col block
  const int tiles = L >> 6;
  const int b = blockIdx.x / tiles;
  const int t0 = (blockIdx.x % tiles) << 6;

  // stage A tile: padded rows [t0 .. t0+65] are contiguous = 33792 bytes
  const char* Asrc = (const char*)(Ap + ((size_t)b * (L + 2) + t0) * 256);
#pragma unroll
  for (int j = 0; j < 9; ++j) {
    int off = j * 4096 + tid * 16;
    if (j < 8 || tid < 64) {
      int so = off ^ (((off >> 9) & 7) << 4);
      async16(Asrc + so, lA + off);
    }
  }

  // per-lane weight bases: f = wn*64 + ni*16 + (lane&15), col-chunk = (lane>>4)*16 bytes
  const char* Bb[4];
#pragma unroll
  for (int ni = 0; ni < 4; ++ni)
    Bb[ni] = (const char*)Wp + (size_t)((wn << 6) + (ni << 4) + (lane & 15)) * 1536 +
             ((lane >> 4) << 4);

  f32x4 acc[4][4];
  const f32x4 zero4 = {0.f, 0.f, 0.f, 0.f};
#pragma unroll
  for (int i = 0; i < 4; ++i)
#pragma unroll
    for (int j = 0; j < 4; ++j) acc[i][j] = zero4;

  __syncthreads();  // waits vmcnt(0): A tile resident

  const int rlane = lane & 15;
  const int colp = (lane >> 4) << 4;
#pragma unroll 1
  for (int tap = 0; tap < 3; ++tap) {
    const int xorv = ((tap + rlane) & 7) << 4;
    const int bofs = tap * 512;
#pragma unroll
    for (int ks = 0; ks < 8; ++ks) {
      short8 av[4], bv[4];
#pragma unroll
      for (int ni = 0; ni < 4; ++ni)
        bv[ni] = *(const short8*)(Bb[ni] + bofs + (ks << 6));
#pragma unroll
      for (int mi = 0; mi < 4; ++mi) {
        int a = (tap + (mi << 4) + rlane) * 512 + (ks << 6) + colp;
        av[mi] = *(const short8*)(lA + (a ^ xorv));
      }
#pragma unroll
      for (int mi = 0; mi < 4; ++mi)
#pragma unroll
        for (int ni = 0; ni < 4; ++ni)
          acc[mi][ni] =
              __builtin_amdgcn_mfma_f32_16x16x32_bf16(av[mi], bv[ni], acc[mi][ni], 0, 0, 0);
    }
  }

  // ---- epilogue: bias + ReLU + LN stats over 256 cols ----
  const int cb0 = (wn << 6) + rlane;
  float bi[4], gg[4], bb[4];
#pragma unroll
  for (int ni = 0; ni < 4; ++ni) {
    int col = cb0 + (ni << 4);
    bi[ni] = bias[col]; gg[ni] = gamma[col]; bb[ni] = beta[col];
  }
  const int rbase = (lane >> 4) << 2;
#pragma unroll
  for (int mi = 0; mi < 4; ++mi) {
#pragma unroll
    for (int j = 0; j < 4; ++j) {
      float s = 0.f, s2 = 0.f;
#pragma unroll
      for (int ni = 0; ni < 4; ++ni) {
        float r = fmaxf(acc[mi][ni][j] + bi[ni], 0.f);
        s += r; s2 += r * r;
      }
#pragma unroll
      for (int d = 1; d < 16; d <<= 1) { s += __shfl_xor(s, d); s2 += __shfl_xor(s2, d); }
      if ((lane & 15) == 0) {
        int row = (mi << 4) + rbase + j;
        lred[row * 8 + wn] = s;
        lred[row * 8 + 4 + wn] = s2;
      }
    }
  }
  __syncthreads();
  if (tid < 64) {
    float s = lred[tid * 8] + lred[tid * 8 + 1] + lred[tid * 8 + 2] + lred[tid * 8 + 3];
    float s2 = lred[tid * 8 + 4] + lred[tid * 8 + 5] + lred[tid * 8 + 6] + lred[tid * 8 + 7];
    float mean = s * (1.f / 256.f);
    float var = fmaxf(s2 * (1.f / 256.f) - mean * mean, 0.f);
    lstat[tid * 2] = mean;
    lstat[tid * 2 + 1] = rsqrtf(var + 1e-5f);
  }
  __syncthreads();

  if constexpr (EPI == 0) {
#pragma unroll
    for (int mi = 0; mi < 4; ++mi) {
#pragma unroll
      for (int j = 0; j < 4; ++j) {
        int row = (mi << 4) + rbase + j;
        float mean = lstat[row * 2], rstd = lstat[row * 2 + 1];
        __hip_bfloat16* hp = Hout + ((size_t)b * (L + 2) + t0 + row + 1) * 256 + cb0;
#pragma unroll
        for (int ni = 0; ni < 4; ++ni) {
          float r = fmaxf(acc[mi][ni][j] + bi[ni], 0.f);
          hp[ni << 4] = __float2bfloat16((r - mean) * rstd * gg[ni] + bb[ni]);
        }
      }
    }
  } else {
    float wlv[4];
#pragma unroll
    for (int ni = 0; ni < 4; ++ni) wlv[ni] = wl[cb0 + (ni << 4)];
#pragma unroll
    for (int mi = 0; mi < 4; ++mi) {
#pragma unroll
      for (int j = 0; j < 4; ++j) {
        int row = (mi << 4) + rbase + j;
        float mean = lstat[row * 2], rstd = lstat[row * 2 + 1];
        float ds = 0.f;
#pragma unroll
        for (int ni = 0; ni < 4; ++ni) {
          float r = fmaxf(acc[mi][ni][j] + bi[ni], 0.f);
          ds += ((r - mean) * rstd * gg[ni] + bb[ni]) * wlv[ni];
        }
#pragma unroll
        for (int d = 1; d < 16; d <<= 1) ds += __shfl_xor(ds, d);
        if ((lane & 15) == 0) lred[row * 8 + wn] = ds;
      }
    }
    __syncthreads();
    if (tid < 64) {
      float z = lred[tid * 8] + lred[tid * 8 + 1] + lred[tid * 8 + 2] + lred[tid * 8 + 3] + blp[0];
      Sout[(size_t)b * L + t0 + tid] = fmaxf(z, 0.f);
    }
  }
}

extern "C" void kernel_launch(void* const* d_in, const int* in_sizes, int n_in,
                              void* d_out, int out_size, void* d_ws, size_t ws_size,
                              hipStream_t stream) {
  const float* x = (const float*)d_in[0];
  const int* dur = (const int*)d_in[1];
  const float* tp = (const float*)d_in[2];
  const float* te = (const float*)d_in[3];
  const float* pq = (const float*)d_in[5];
  const float* eq = (const float*)d_in[6];
  const float* pemb = (const float*)d_in[37];
  const float* eemb = (const float*)d_in[38];

  char* ws = (char*)d_ws;
  __hip_bfloat16* wpb = (__hip_bfloat16*)ws;                 // 6 x [256][768] bf16
  __hip_bfloat16* wp[6];
  for (int i = 0; i < 6; ++i) wp[i] = wpb + (size_t)i * 196608;
  __hip_bfloat16* xb = (__hip_bfloat16*)(ws + 2359296);      // [32][258][256]
  __hip_bfloat16* h1dp = (__hip_bfloat16*)(ws + 6586368);    // [32][258][256]
  __hip_bfloat16* M1 = (__hip_bfloat16*)(ws + 10813440);     // [32][2050][256]
  __hip_bfloat16* M2 = (__hip_bfloat16*)(ws + 44400640);     // [32][2050][256]

  float* out = (float*)d_out;

  zero2_kernel<<<256, 256, 0, stream>>>(xb, h1dp, M1, M2);
  packall_kernel<<<1536, 256, 0, stream>>>((const float*)d_in[7], (const float*)d_in[11],
                                           (const float*)d_in[17], (const float*)d_in[21],
                                           (const float*)d_in[27], (const float*)d_in[31], wpb);
  cvt_pad_kernel<<<2048, 256, 0, stream>>>(x, xb);

  // duration predictor (L=256)
  pred_gemm<0><<<128, 256, 0, stream>>>(xb, wp[0], (const float*)d_in[8], (const float*)d_in[9],
                                        (const float*)d_in[10], nullptr, nullptr, h1dp, nullptr,
                                        256);
  pred_gemm<1><<<128, 256, 0, stream>>>(h1dp, wp[1], (const float*)d_in[12],
                                        (const float*)d_in[13], (const float*)d_in[14],
                                        (const float*)d_in[15], (const float*)d_in[16], nullptr,
                                        out + DUR_OFF, 256);

  // length regulate (true durations) -> M1 bf16; mel_len
  gather_kernel<<<1024, 256, 0, stream>>>(x, dur, M1, out + MEL_OFF);

  // pitch predictor (L=2048): M1 -> M2 -> pitches
  pred_gemm<0><<<1024, 256, 0, stream>>>(M1, wp[2], (const float*)d_in[18], (const float*)d_in[19],
                                         (const float*)d_in[20], nullptr, nullptr, M2, nullptr,
                                         2048);
  pred_gemm<1><<<1024, 256, 0, stream>>>(M2, wp[3], (const float*)d_in[22], (const float*)d_in[23],
                                         (const float*)d_in[24], (const float*)d_in[25],
                                         (const float*)d_in[26], nullptr, out + PIT_OFF, 2048);

  // fused embedding adds: M2 = bf16(M1+pemb), out = M1+pemb+eemb (f32)
  addemb_kernel<<<1024, 256, 0, stream>>>(tp, te, pq, eq, pemb, eemb, M1, M2, out);

  // energy predictor (L=2048): M2 -> M1 -> energies
  pred_gemm<0><<<1024, 256, 0, stream>>>(M2, wp[4], (const float*)d_in[28], (const float*)d_in[29],
                                         (const float*)d_in[30], nullptr, nullptr, M1, nullptr,
                                         2048);
  pred_gemm<1><<<1024, 256, 0, stream>>>(M1, wp[5], (const float*)d_in[32], (const float*)d_in[33],
                                         (const float*)d_in[34], (const float*)d_in[35],
                                         (const float*)d_in[36], nullptr, out + ENE_OFF, 2048);
}

// Round 3
// 388.154 us; speedup vs baseline: 1.1925x; 1.1925x over previous
//
#include <hip/hip_runtime.h>
#include <hip/hip_bf16.h>
#include <stdint.h>

// Problem constants: B=32, T=256, M=2048, C=F=256, K=3 (pad 1), NB=256
#define DUR_OFF 16777216
#define PIT_OFF 16785408
#define ENE_OFF 16850944
#define MEL_OFF 16916480

typedef __attribute__((ext_vector_type(8))) short short8;
typedef __attribute__((ext_vector_type(4))) float f32x4;

__device__ __forceinline__ void async16(const void* g, void* l) {
  __builtin_amdgcn_global_load_lds((__attribute__((address_space(1))) void*)g,
                                   (__attribute__((address_space(3))) void*)l, 16, 0, 0);
}

__device__ __forceinline__ unsigned short bfu(float f) {
  __hip_bfloat16 h = __float2bfloat16(f);
  return __builtin_bit_cast(unsigned short, h);
}
__device__ __forceinline__ float f_from_bf(unsigned short u) {
  return __builtin_bit_cast(float, (unsigned)u << 16);
}

// Zero the two pad rows (t=-1, t=L) of all four padded [B][L+2][256] bf16 buffers.
__global__ void zero2_kernel(__hip_bfloat16* __restrict__ xb, __hip_bfloat16* __restrict__ h1,
                             __hip_bfloat16* __restrict__ M1, __hip_bfloat16* __restrict__ M2) {
  int buf = blockIdx.x >> 6, sub = blockIdx.x & 63;
  int b = sub >> 1, top = sub & 1;
  __hip_bfloat16* p; int L;
  if (buf == 0) { p = xb; L = 256; }
  else if (buf == 1) { p = h1; L = 256; }
  else if (buf == 2) { p = M1; L = 2048; }
  else { p = M2; L = 2048; }
  size_t row = (size_t)b * (L + 2) + (top ? (L + 1) : 0);
  p[row * 256 + threadIdx.x] = __float2bfloat16(0.0f);
}

// Pack all 6 conv weights [F=256][C=256][K=3] f32 (torch OIH) into MFMA-fragment-linear
// bf16 layout: Wfrag[wsel][fb][ni][tap][ks][lane][e], 16 B per (.. lane) chunk, so a wave's
// B-fragment load is base + lane*16 (fully coalesced 1 KB).
//   f = fb*64 + ni*16 + (lane&15);  c = ks*32 + (lane>>4)*8 + e;  kk = tap*256 + c
__global__ void packfrag_kernel(const float* __restrict__ w0, const float* __restrict__ w1,
                                const float* __restrict__ w2, const float* __restrict__ w3,
                                const float* __restrict__ w4, const float* __restrict__ w5,
                                __hip_bfloat16* __restrict__ wpbase) {
  int t = blockIdx.x * 256 + threadIdx.x;   // 147456 total = 6 * 24576 chunks
  int wsel = t / 24576;
  int rem = t % 24576;
  const float* w = wsel == 0 ? w0 : wsel == 1 ? w1 : wsel == 2 ? w2
                 : wsel == 3 ? w3 : wsel == 4 ? w4 : w5;
  __hip_bfloat16* wp = wpbase + (size_t)wsel * 196608;
  int L = rem & 63;
  int ks = (rem >> 6) & 7;
  int q = rem >> 9;            // (fb*4+ni)*3 + tap
  int tap = q % 3, r = q / 3;
  int ni = r & 3, fb = r >> 2;
  int f = fb * 64 + ni * 16 + (L & 15);
  int cb = ks * 32 + ((L >> 4) << 3);
  short8 o;
#pragma unroll
  for (int e = 0; e < 8; ++e)
    o[e] = (short)bfu(w[((size_t)f * 256 + cb + e) * 3 + tap]);
  *(short8*)(wp + (size_t)rem * 8) = o;
}

// x [32][256][256] f32 -> xb [32][258][256] bf16 (row t -> padded row t+1)
__global__ void cvt_pad_kernel(const float* __restrict__ x, __hip_bfloat16* __restrict__ xb) {
  int idx = blockIdx.x * 256 + threadIdx.x;
  float4 v = ((const float4*)x)[idx];
  int c4 = idx & 63;
  int rowi = idx >> 6;
  int b = rowi >> 8, t = rowi & 255;
  ushort4 o;
  o.x = bfu(v.x); o.y = bfu(v.y); o.z = bfu(v.z); o.w = bfu(v.w);
  ((ushort4*)(xb + ((size_t)b * 258 + t + 1) * 256))[c4] = o;
}

// Length regulate (in-block cumsum of true_duration) -> bf16 padded M1; chunk0 writes mel_len.
__global__ void gather_kernel(const float* __restrict__ x, const int* __restrict__ dur,
                              __hip_bfloat16* __restrict__ outB, float* __restrict__ mel) {
  __shared__ int scs[256];
  __shared__ int sidx[64];
  __shared__ int sval[64];
  int bch = blockIdx.x >> 5;
  int m0 = (blockIdx.x & 31) << 6;
  int tid = threadIdx.x;
  scs[tid] = dur[bch * 256 + tid];
  __syncthreads();
  for (int off = 1; off < 256; off <<= 1) {
    int add = (tid >= off) ? scs[tid - off] : 0;
    __syncthreads();
    scs[tid] += add;
    __syncthreads();
  }
  int total = scs[255];
  if (tid == 0 && (blockIdx.x & 31) == 0)
    mel[bch] = (float)(total < 2048 ? total : 2048);
  if (tid < 64) {
    int m = m0 + tid;
    int lo = 0, hi = 256;
    while (lo < hi) { int mid = (lo + hi) >> 1; if (scs[mid] <= m) lo = mid + 1; else hi = mid; }
    sidx[tid] = lo < 255 ? lo : 255;
    sval[tid] = (m < total);
  }
  __syncthreads();
  int lane = tid & 63, rs = tid >> 6;
  for (int r = rs; r < 64; r += 4) {
    float4 v = make_float4(0.f, 0.f, 0.f, 0.f);
    if (sval[r]) v = ((const float4*)(x + ((size_t)bch * 256 + sidx[r]) * 256))[lane];
    ushort4 o;
    o.x = bfu(v.x); o.y = bfu(v.y); o.z = bfu(v.z); o.w = bfu(v.w);
    ((ushort4*)(outB + ((size_t)bch * 2050 + m0 + r + 1) * 256))[lane] = o;
  }
}

// Fused double embedding add: M2 = bf16(M1 + pemb[idx_p]); out = (M1 + pemb) + eemb[idx_e] (f32)
__global__ void addemb_kernel(const float* __restrict__ tp, const float* __restrict__ te,
                              const float* __restrict__ pq, const float* __restrict__ eq,
                              const float* __restrict__ pemb, const float* __restrict__ eemb,
                              const __hip_bfloat16* __restrict__ M1, __hip_bfloat16* __restrict__ M2,
                              float* __restrict__ out) {
  __shared__ float sp[255], se[255];
  __shared__ int sip[64], sie[64];
  int bch = blockIdx.x >> 5;
  int m0 = (blockIdx.x & 31) << 6;
  int tid = threadIdx.x;
  if (tid < 255) { sp[tid] = pq[tid]; se[tid] = eq[tid]; }
  __syncthreads();
  if (tid < 64) {
    float xv = tp[bch * 2048 + m0 + tid];
    int lo = 0, hi = 255;
    while (lo < hi) { int mid = (lo + hi) >> 1; if (sp[mid] <= xv) lo = mid + 1; else hi = mid; }
    sip[tid] = lo;
    float ev = te[bch * 2048 + m0 + tid];
    lo = 0; hi = 255;
    while (lo < hi) { int mid = (lo + hi) >> 1; if (se[mid] <= ev) lo = mid + 1; else hi = mid; }
    sie[tid] = lo;
  }
  __syncthreads();
  int lane = tid & 63, rs = tid >> 6;
  for (int r = rs; r < 64; r += 4) {
    ushort4 mv = ((const ushort4*)(M1 + ((size_t)bch * 2050 + m0 + r + 1) * 256))[lane];
    float4 ep = ((const float4*)(pemb + (size_t)sip[r] * 256))[lane];
    float4 ee = ((const float4*)(eemb + (size_t)sie[r] * 256))[lane];
    float4 v;
    v.x = f_from_bf(mv.x) + ep.x; v.y = f_from_bf(mv.y) + ep.y;
    v.z = f_from_bf(mv.z) + ep.z; v.w = f_from_bf(mv.w) + ep.w;
    ushort4 o;
    o.x = bfu(v.x); o.y = bfu(v.y); o.z = bfu(v.z); o.w = bfu(v.w);
    ((ushort4*)(M2 + ((size_t)bch * 2050 + m0 + r + 1) * 256))[lane] = o;
    float4 w;
    w.x = v.x + ee.x; w.y = v.y + ee.y; w.z = v.z + ee.z; w.w = v.w + ee.w;
    ((float4*)(out + ((size_t)bch * 2048 + m0 + r) * 256))[lane] = w;
  }
}

// Fused conv1d(K=3,'same') + bias + ReLU + LayerNorm GEMM, 128x256 tile per block (4 waves,
// wave = 64-col block, acc[8][4]).
// A tile (130 padded rows x 512 B = 65 KB) staged ONCE via global_load_lds with XOR-swizzled
// source (swz(a) = a ^ (((a>>9)&7)<<4), involution); ONE barrier; then 24 K-slices of
// {4 coalesced 1KB B-fragment loads from fragment-linear Wfrag (L2-resident, no LDS) +
//  8 swizzled ds_read_b128 (A) + 32 MFMA}, no further barriers.
// EPI==0: store LN result bf16 into padded Hout. EPI==1: fold Linear(F->1)+ReLU -> Sout.
template <int EPI>
__global__ __launch_bounds__(256, 2)
void pred_gemm(const __hip_bfloat16* __restrict__ Ap, const __hip_bfloat16* __restrict__ Wf,
               const float* __restrict__ bias, const float* __restrict__ gamma,
               const float* __restrict__ beta, const float* __restrict__ wl,
               const float* __restrict__ blp, __hip_bfloat16* __restrict__ Hout,
               float* __restrict__ Sout, int L) {
  __shared__ char lA[66560];       // 130 rows x 512 B (swizzled)
  __shared__ float lred[128 * 8];
  __shared__ float lstat[128 * 2];

  const int tid = threadIdx.x;
  const int wid = tid >> 6;
  const int lane = tid & 63;
  const int wn = wid;              // wave -> 64-col block
  const int tiles = L >> 7;
  const int b = blockIdx.x / tiles;
  const int t0 = (blockIdx.x % tiles) << 7;

  // stage A tile: padded rows [t0 .. t0+129] contiguous = 66560 bytes
  const char* Asrc = (const char*)(Ap + ((size_t)b * (L + 2) + t0) * 256);
#pragma unroll
  for (int j = 0; j < 17; ++j) {
    int off = j * 4096 + tid * 16;
    if (j < 16 || tid < 64) {
      int so = off ^ (((off >> 9) & 7) << 4);
      async16(Asrc + so, lA + off);
    }
  }

  // per-lane fragment-linear weight base for this wave's 64-col block
  const char* Wb = (const char*)Wf + (size_t)wn * 98304 + lane * 16;

  f32x4 acc[8][4];
  const f32x4 zero4 = {0.f, 0.f, 0.f, 0.f};
#pragma unroll
  for (int i = 0; i < 8; ++i)
#pragma unroll
    for (int j = 0; j < 4; ++j) acc[i][j] = zero4;

  __syncthreads();  // waits vmcnt(0): A tile resident

  const int rlane = lane & 15;
  const int colp = (lane >> 4) << 4;
#pragma unroll 1
  for (int tap = 0; tap < 3; ++tap) {
    const int xorv = ((tap + rlane) & 7) << 4;
#pragma unroll
    for (int ks = 0; ks < 8; ++ks) {
      short8 av[8], bv[4];
#pragma unroll
      for (int ni = 0; ni < 4; ++ni)
        bv[ni] = *(const short8*)(Wb + (((ni * 3 + tap) * 8 + ks) << 10));
#pragma unroll
      for (int mi = 0; mi < 8; ++mi) {
        int a = (tap + (mi << 4) + rlane) * 512 + (ks << 6) + colp;
        av[mi] = *(const short8*)(lA + (a ^ xorv));
      }
#pragma unroll
      for (int mi = 0; mi < 8; ++mi)
#pragma unroll
        for (int ni = 0; ni < 4; ++ni)
          acc[mi][ni] =
              __builtin_amdgcn_mfma_f32_16x16x32_bf16(av[mi], bv[ni], acc[mi][ni], 0, 0, 0);
    }
  }

  // ---- epilogue: bias + ReLU + LN stats over 256 cols ----
  const int cb0 = (wn << 6) + rlane;
  float bi[4], gg[4], bb[4];
#pragma unroll
  for (int ni = 0; ni < 4; ++ni) {
    int col = cb0 + (ni << 4);
    bi[ni] = bias[col]; gg[ni] = gamma[col]; bb[ni] = beta[col];
  }
  const int rbase = (lane >> 4) << 2;
#pragma unroll
  for (int mi = 0; mi < 8; ++mi) {
#pragma unroll
    for (int j = 0; j < 4; ++j) {
      float s = 0.f, s2 = 0.f;
#pragma unroll
      for (int ni = 0; ni < 4; ++ni) {
        float r = fmaxf(acc[mi][ni][j] + bi[ni], 0.f);
        s += r; s2 += r * r;
      }
#pragma unroll
      for (int d = 1; d < 16; d <<= 1) { s += __shfl_xor(s, d); s2 += __shfl_xor(s2, d); }
      if ((lane & 15) == 0) {
        int row = (mi << 4) + rbase + j;
        lred[row * 8 + wn] = s;
        lred[row * 8 + 4 + wn] = s2;
      }
    }
  }
  __syncthreads();
  if (tid < 128) {
    float s = lred[tid * 8] + lred[tid * 8 + 1] + lred[tid * 8 + 2] + lred[tid * 8 + 3];
    float s2 = lred[tid * 8 + 4] + lred[tid * 8 + 5] + lred[tid * 8 + 6] + lred[tid * 8 + 7];
    float mean = s * (1.f / 256.f);
    float var = fmaxf(s2 * (1.f / 256.f) - mean * mean, 0.f);
    lstat[tid * 2] = mean;
    lstat[tid * 2 + 1] = rsqrtf(var + 1e-5f);
  }
  __syncthreads();

  if constexpr (EPI == 0) {
#pragma unroll
    for (int mi = 0; mi < 8; ++mi) {
#pragma unroll
      for (int j = 0; j < 4; ++j) {
        int row = (mi << 4) + rbase + j;
        float mean = lstat[row * 2], rstd = lstat[row * 2 + 1];
        __hip_bfloat16* hp = Hout + ((size_t)b * (L + 2) + t0 + row + 1) * 256 + cb0;
#pragma unroll
        for (int ni = 0; ni < 4; ++ni) {
          float r = fmaxf(acc[mi][ni][j] + bi[ni], 0.f);
          hp[ni << 4] = __float2bfloat16((r - mean) * rstd * gg[ni] + bb[ni]);
        }
      }
    }
  } else {
    float wlv[4];
#pragma unroll
    for (int ni = 0; ni < 4; ++ni) wlv[ni] = wl[cb0 + (ni << 4)];
#pragma unroll
    for (int mi = 0; mi < 8; ++mi) {
#pragma unroll
      for (int j = 0; j < 4; ++j) {
        int row = (mi << 4) + rbase + j;
        float mean = lstat[row * 2], rstd = lstat[row * 2 + 1];
        float ds = 0.f;
#pragma unroll
        for (int ni = 0; ni < 4; ++ni) {
          float r = fmaxf(acc[mi][ni][j] + bi[ni], 0.f);
          ds += ((r - mean) * rstd * gg[ni] + bb[ni]) * wlv[ni];
        }
#pragma unroll
        for (int d = 1; d < 16; d <<= 1) ds += __shfl_xor(ds, d);
        if ((lane & 15) == 0) lred[row * 8 + wn] = ds;
      }
    }
    __syncthreads();
    if (tid < 128) {
      float z = lred[tid * 8] + lred[tid * 8 + 1] + lred[tid * 8 + 2] + lred[tid * 8 + 3] + blp[0];
      Sout[(size_t)b * L + t0 + tid] = fmaxf(z, 0.f);
    }
  }
}

extern "C" void kernel_launch(void* const* d_in, const int* in_sizes, int n_in,
                              void* d_out, int out_size, void* d_ws, size_t ws_size,
                              hipStream_t stream) {
  const float* x = (const float*)d_in[0];
  const int* dur = (const int*)d_in[1];
  const float* tp = (const float*)d_in[2];
  const float* te = (const float*)d_in[3];
  const float* pq = (const float*)d_in[5];
  const float* eq = (const float*)d_in[6];
  const float* pemb = (const float*)d_in[37];
  const float* eemb = (const float*)d_in[38];

  char* ws = (char*)d_ws;
  __hip_bfloat16* wpb = (__hip_bfloat16*)ws;                 // 6 x 196608 bf16 (fragment-linear)
  __hip_bfloat16* wp[6];
  for (int i = 0; i < 6; ++i) wp[i] = wpb + (size_t)i * 196608;
  __hip_bfloat16* xb = (__hip_bfloat16*)(ws + 2359296);      // [32][258][256]
  __hip_bfloat16* h1dp = (__hip_bfloat16*)(ws + 6586368);    // [32][258][256]
  __hip_bfloat16* M1 = (__hip_bfloat16*)(ws + 10813440);     // [32][2050][256]
  __hip_bfloat16* M2 = (__hip_bfloat16*)(ws + 44400640);     // [32][2050][256]

  float* out = (float*)d_out;

  zero2_kernel<<<256, 256, 0, stream>>>(xb, h1dp, M1, M2);
  packfrag_kernel<<<576, 256, 0, stream>>>((const float*)d_in[7], (const float*)d_in[11],
                                           (const float*)d_in[17], (const float*)d_in[21],
                                           (const float*)d_in[27], (const float*)d_in[31], wpb);
  cvt_pad_kernel<<<2048, 256, 0, stream>>>(x, xb);

  // duration predictor (L=256)
  pred_gemm<0><<<64, 256, 0, stream>>>(xb, wp[0], (const float*)d_in[8], (const float*)d_in[9],
                                       (const float*)d_in[10], nullptr, nullptr, h1dp, nullptr,
                                       256);
  pred_gemm<1><<<64, 256, 0, stream>>>(h1dp, wp[1], (const float*)d_in[12],
                                       (const float*)d_in[13], (const float*)d_in[14],
                                       (const float*)d_in[15], (const float*)d_in[16], nullptr,
                                       out + DUR_OFF, 256);

  // length regulate (true durations) -> M1 bf16; mel_len
  gather_kernel<<<1024, 256, 0, stream>>>(x, dur, M1, out + MEL_OFF);

  // pitch predictor (L=2048): M1 -> M2 -> pitches
  pred_gemm<0><<<512, 256, 0, stream>>>(M1, wp[2], (const float*)d_in[18], (const float*)d_in[19],
                                        (const float*)d_in[20], nullptr, nullptr, M2, nullptr,
                                        2048);
  pred_gemm<1><<<512, 256, 0, stream>>>(M2, wp[3], (const float*)d_in[22], (const float*)d_in[23],
                                        (const float*)d_in[24], (const float*)d_in[25],
                                        (const float*)d_in[26], nullptr, out + PIT_OFF, 2048);

  // fused embedding adds: M2 = bf16(M1+pemb), out = M1+pemb+eemb (f32)
  addemb_kernel<<<1024, 256, 0, stream>>>(tp, te, pq, eq, pemb, eemb, M1, M2, out);

  // energy predictor (L=2048): M2 -> M1 -> energies
  pred_gemm<0><<<512, 256, 0, stream>>>(M2, wp[4], (const float*)d_in[28], (const float*)d_in[29],
                                        (const float*)d_in[30], nullptr, nullptr, M1, nullptr,
                                        2048);
  pred_gemm<1><<<512, 256, 0, stream>>>(M1, wp[5], (const float*)d_in[32], (const float*)d_in[33],
                                        (const float*)d_in[34], (const float*)d_in[35],
                                        (const float*)d_in[36], nullptr, out + ENE_OFF, 2048);
}

// Round 5
// 375.193 us; speedup vs baseline: 1.2337x; 1.0345x over previous
//
#include <hip/hip_runtime.h>
#include <hip/hip_bf16.h>
#include <stdint.h>

// Problem constants: B=32, T=256, M=2048, C=F=256, K=3 (pad 1), NB=256
#define DUR_OFF 16777216
#define PIT_OFF 16785408
#define ENE_OFF 16850944
#define MEL_OFF 16916480

typedef __attribute__((ext_vector_type(8))) short short8;
typedef __attribute__((ext_vector_type(4))) float f32x4;

__device__ __forceinline__ void async16(const void* g, void* l) {
  __builtin_amdgcn_global_load_lds((__attribute__((address_space(1))) void*)g,
                                   (__attribute__((address_space(3))) void*)l, 16, 0, 0);
}

__device__ __forceinline__ unsigned short bfu(float f) {
  __hip_bfloat16 h = __float2bfloat16(f);
  return __builtin_bit_cast(unsigned short, h);
}
__device__ __forceinline__ float f_from_bf(unsigned short u) {
  return __builtin_bit_cast(float, (unsigned)u << 16);
}

// Zero the two pad rows (t=-1, t=L) of all four padded [B][L+2][256] bf16 buffers.
__global__ void zero2_kernel(__hip_bfloat16* __restrict__ xb, __hip_bfloat16* __restrict__ h1,
                             __hip_bfloat16* __restrict__ M1, __hip_bfloat16* __restrict__ M2) {
  int buf = blockIdx.x >> 6, sub = blockIdx.x & 63;
  int b = sub >> 1, top = sub & 1;
  __hip_bfloat16* p; int L;
  if (buf == 0) { p = xb; L = 256; }
  else if (buf == 1) { p = h1; L = 256; }
  else if (buf == 2) { p = M1; L = 2048; }
  else { p = M2; L = 2048; }
  size_t row = (size_t)b * (L + 2) + (top ? (L + 1) : 0);
  p[row * 256 + threadIdx.x] = __float2bfloat16(0.0f);
}

// Pack all 6 conv weights [F=256][C=256][K=3] f32 (torch OIH) into MFMA-fragment-linear
// bf16 layout: Wfrag[wsel][fb][ni][tap][ks][lane][e], 16 B per (.. lane) chunk, so a wave's
// B-fragment load is base + lane*16 (fully coalesced 1 KB).
//   f = fb*64 + ni*16 + (lane&15);  c = ks*32 + (lane>>4)*8 + e;  kk = tap*256 + c
__global__ void packfrag_kernel(const float* __restrict__ w0, const float* __restrict__ w1,
                                const float* __restrict__ w2, const float* __restrict__ w3,
                                const float* __restrict__ w4, const float* __restrict__ w5,
                                __hip_bfloat16* __restrict__ wpbase) {
  int t = blockIdx.x * 256 + threadIdx.x;   // 147456 total = 6 * 24576 chunks
  int wsel = t / 24576;
  int rem = t % 24576;
  const float* w = wsel == 0 ? w0 : wsel == 1 ? w1 : wsel == 2 ? w2
                 : wsel == 3 ? w3 : wsel == 4 ? w4 : w5;
  __hip_bfloat16* wp = wpbase + (size_t)wsel * 196608;
  int L = rem & 63;
  int ks = (rem >> 6) & 7;
  int q = rem >> 9;            // (fb*4+ni)*3 + tap
  int tap = q % 3, r = q / 3;
  int ni = r & 3, fb = r >> 2;
  int f = fb * 64 + ni * 16 + (L & 15);
  int cb = ks * 32 + ((L >> 4) << 3);
  short8 o;
#pragma unroll
  for (int e = 0; e < 8; ++e)
    o[e] = (short)bfu(w[((size_t)f * 256 + cb + e) * 3 + tap]);
  *(short8*)(wp + (size_t)rem * 8) = o;
}

// x [32][256][256] f32 -> xb [32][258][256] bf16 (row t -> padded row t+1)
__global__ void cvt_pad_kernel(const float* __restrict__ x, __hip_bfloat16* __restrict__ xb) {
  int idx = blockIdx.x * 256 + threadIdx.x;
  float4 v = ((const float4*)x)[idx];
  int c4 = idx & 63;
  int rowi = idx >> 6;
  int b = rowi >> 8, t = rowi & 255;
  ushort4 o;
  o.x = bfu(v.x); o.y = bfu(v.y); o.z = bfu(v.z); o.w = bfu(v.w);
  ((ushort4*)(xb + ((size_t)b * 258 + t + 1) * 256))[c4] = o;
}

// Length regulate (in-block cumsum of true_duration) -> bf16 padded M1; chunk0 writes mel_len.
__global__ void gather_kernel(const float* __restrict__ x, const int* __restrict__ dur,
                              __hip_bfloat16* __restrict__ outB, float* __restrict__ mel) {
  __shared__ int scs[256];
  __shared__ int sidx[64];
  __shared__ int sval[64];
  int bch = blockIdx.x >> 5;
  int m0 = (blockIdx.x & 31) << 6;
  int tid = threadIdx.x;
  scs[tid] = dur[bch * 256 + tid];
  __syncthreads();
  for (int off = 1; off < 256; off <<= 1) {
    int add = (tid >= off) ? scs[tid - off] : 0;
    __syncthreads();
    scs[tid] += add;
    __syncthreads();
  }
  int total = scs[255];
  if (tid == 0 && (blockIdx.x & 31) == 0)
    mel[bch] = (float)(total < 2048 ? total : 2048);
  if (tid < 64) {
    int m = m0 + tid;
    int lo = 0, hi = 256;
    while (lo < hi) { int mid = (lo + hi) >> 1; if (scs[mid] <= m) lo = mid + 1; else hi = mid; }
    sidx[tid] = lo < 255 ? lo : 255;
    sval[tid] = (m < total);
  }
  __syncthreads();
  int lane = tid & 63, rs = tid >> 6;
  for (int r = rs; r < 64; r += 4) {
    float4 v = make_float4(0.f, 0.f, 0.f, 0.f);
    if (sval[r]) v = ((const float4*)(x + ((size_t)bch * 256 + sidx[r]) * 256))[lane];
    ushort4 o;
    o.x = bfu(v.x); o.y = bfu(v.y); o.z = bfu(v.z); o.w = bfu(v.w);
    ((ushort4*)(outB + ((size_t)bch * 2050 + m0 + r + 1) * 256))[lane] = o;
  }
}

// Fused double embedding add: M2 = bf16(M1 + pemb[idx_p]); out = (M1 + pemb) + eemb[idx_e] (f32)
__global__ void addemb_kernel(const float* __restrict__ tp, const float* __restrict__ te,
                              const float* __restrict__ pq, const float* __restrict__ eq,
                              const float* __restrict__ pemb, const float* __restrict__ eemb,
                              const __hip_bfloat16* __restrict__ M1, __hip_bfloat16* __restrict__ M2,
                              float* __restrict__ out) {
  __shared__ float sp[255], se[255];
  __shared__ int sip[64], sie[64];
  int bch = blockIdx.x >> 5;
  int m0 = (blockIdx.x & 31) << 6;
  int tid = threadIdx.x;
  if (tid < 255) { sp[tid] = pq[tid]; se[tid] = eq[tid]; }
  __syncthreads();
  if (tid < 64) {
    float xv = tp[bch * 2048 + m0 + tid];
    int lo = 0, hi = 255;
    while (lo < hi) { int mid = (lo + hi) >> 1; if (sp[mid] <= xv) lo = mid + 1; else hi = mid; }
    sip[tid] = lo;
    float ev = te[bch * 2048 + m0 + tid];
    lo = 0; hi = 255;
    while (lo < hi) { int mid = (lo + hi) >> 1; if (se[mid] <= ev) lo = mid + 1; else hi = mid; }
    sie[tid] = lo;
  }
  __syncthreads();
  int lane = tid & 63, rs = tid >> 6;
  for (int r = rs; r < 64; r += 4) {
    ushort4 mv = ((const ushort4*)(M1 + ((size_t)bch * 2050 + m0 + r + 1) * 256))[lane];
    float4 ep = ((const float4*)(pemb + (size_t)sip[r] * 256))[lane];
    float4 ee = ((const float4*)(eemb + (size_t)sie[r] * 256))[lane];
    float4 v;
    v.x = f_from_bf(mv.x) + ep.x; v.y = f_from_bf(mv.y) + ep.y;
    v.z = f_from_bf(mv.z) + ep.z; v.w = f_from_bf(mv.w) + ep.w;
    ushort4 o;
    o.x = bfu(v.x); o.y = bfu(v.y); o.z = bfu(v.z); o.w = bfu(v.w);
    ((ushort4*)(M2 + ((size_t)bch * 2050 + m0 + r + 1) * 256))[lane] = o;
    float4 w;
    w.x = v.x + ee.x; w.y = v.y + ee.y; w.z = v.z + ee.z; w.w = v.w + ee.w;
    ((float4*)(out + ((size_t)bch * 2048 + m0 + r) * 256))[lane] = w;
  }
}

// Load the 4 B fragments of K-slice s (s = tap*8+ks) for this wave's 64-col block.
__device__ __forceinline__ void loadB4(const char* Wb, int s, short8* dst) {
  int tap = s >> 3, ks = s & 7;
#pragma unroll
  for (int ni = 0; ni < 4; ++ni)
    dst[ni] = *(const short8*)(Wb + ((((ni * 3 + tap) << 3) + ks) << 10));
}

// Fused conv1d(K=3,'same') + bias + ReLU + LayerNorm GEMM, TM x 256 tile per block
// (4 waves, wave = 64-col block, acc[TM/16][4]).
// A tile ((TM+2) rows x 512 B) staged ONCE via global_load_lds with XOR-swizzled source
// (swz(a) = a ^ (((a>>9)&7)<<4), involution); ONE barrier; then 24 K-slices of
// {4 coalesced 1KB B-fragment loads PREFETCHED ONE SLICE AHEAD (double register buffer,
//  issued before the current slice's MFMA cluster so latency hides under compute) +
//  TM/16 swizzled ds_read_b128 (A) + MFMA}, no further barriers.
// EPI==0: store LN result bf16 into padded Hout. EPI==1: fold Linear(F->1)+ReLU -> Sout.
template <int EPI, int TM>
__global__ __launch_bounds__(256, 2)
void pred_gemm(const __hip_bfloat16* __restrict__ Ap, const __hip_bfloat16* __restrict__ Wf,
               const float* __restrict__ bias, const float* __restrict__ gamma,
               const float* __restrict__ beta, const float* __restrict__ wl,
               const float* __restrict__ blp, __hip_bfloat16* __restrict__ Hout,
               float* __restrict__ Sout, int L) {
  constexpr int MI = TM / 16;
  constexpr int ABYTES = (TM + 2) * 512;
  __shared__ char lA[ABYTES];
  __shared__ float lred[TM * 8];
  __shared__ float lstat[TM * 2];

  const int tid = threadIdx.x;
  const int wid = tid >> 6;
  const int lane = tid & 63;
  const int wn = wid;              // wave -> 64-col block
  const int tiles = L / TM;
  const int b = blockIdx.x / tiles;
  const int t0 = (blockIdx.x % tiles) * TM;

  // stage A tile: padded rows [t0 .. t0+TM+1] contiguous = ABYTES
  const char* Asrc = (const char*)(Ap + ((size_t)b * (L + 2) + t0) * 256);
#pragma unroll
  for (int j = 0; j < (ABYTES + 4095) / 4096; ++j) {
    int off = j * 4096 + tid * 16;
    if (off < ABYTES) {
      int so = off ^ (((off >> 9) & 7) << 4);
      async16(Asrc + so, lA + off);
    }
  }

  // per-lane fragment-linear weight base for this wave's 64-col block
  const char* Wb = (const char*)Wf + (size_t)wn * 98304 + lane * 16;

  f32x4 acc[MI][4];
  const f32x4 zero4 = {0.f, 0.f, 0.f, 0.f};
#pragma unroll
  for (int i = 0; i < MI; ++i)
#pragma unroll
    for (int j = 0; j < 4; ++j) acc[i][j] = zero4;

  // prefetch slice 0's B fragments; they drain together with the A staging.
  short8 bA[4], bB[4];
  loadB4(Wb, 0, bA);

  __syncthreads();  // waits vmcnt(0): A tile + slice-0 B resident

  const int rlane = lane & 15;
  const int colp = (lane >> 4) << 4;
#pragma unroll
  for (int s = 0; s < 24; ++s) {
    const int tap = s >> 3, ks = s & 7;
    short8* cur = (s & 1) ? bB : bA;
    short8* nxt = (s & 1) ? bA : bB;
    if (s < 23) loadB4(Wb, s + 1, nxt);   // in flight during this slice's MFMAs
    const int xorv = ((tap + rlane) & 7) << 4;
    short8 av[MI];
#pragma unroll
    for (int mi = 0; mi < MI; ++mi) {
      int a = (tap + (mi << 4) + rlane) * 512 + (ks << 6) + colp;
      av[mi] = *(const short8*)(lA + (a ^ xorv));
    }
#pragma unroll
    for (int mi = 0; mi < MI; ++mi)
#pragma unroll
      for (int ni = 0; ni < 4; ++ni)
        acc[mi][ni] =
            __builtin_amdgcn_mfma_f32_16x16x32_bf16(av[mi], cur[ni], acc[mi][ni], 0, 0, 0);
  }

  // ---- epilogue: bias + ReLU + LN stats over 256 cols ----
  const int cb0 = (wn << 6) + rlane;
  float bi[4], gg[4], bb[4];
#pragma unroll
  for (int ni = 0; ni < 4; ++ni) {
    int col = cb0 + (ni << 4);
    bi[ni] = bias[col]; gg[ni] = gamma[col]; bb[ni] = beta[col];
  }
  const int rbase = (lane >> 4) << 2;
#pragma unroll
  for (int mi = 0; mi < MI; ++mi) {
#pragma unroll
    for (int j = 0; j < 4; ++j) {
      float s = 0.f, s2 = 0.f;
#pragma unroll
      for (int ni = 0; ni < 4; ++ni) {
        float r = fmaxf(acc[mi][ni][j] + bi[ni], 0.f);
        s += r; s2 += r * r;
      }
#pragma unroll
      for (int d = 1; d < 16; d <<= 1) { s += __shfl_xor(s, d); s2 += __shfl_xor(s2, d); }
      if ((lane & 15) == 0) {
        int row = (mi << 4) + rbase + j;
        lred[row * 8 + wn] = s;
        lred[row * 8 + 4 + wn] = s2;
      }
    }
  }
  __syncthreads();
  if (tid < TM) {
    float s = lred[tid * 8] + lred[tid * 8 + 1] + lred[tid * 8 + 2] + lred[tid * 8 + 3];
    float s2 = lred[tid * 8 + 4] + lred[tid * 8 + 5] + lred[tid * 8 + 6] + lred[tid * 8 + 7];
    float mean = s * (1.f / 256.f);
    float var = fmaxf(s2 * (1.f / 256.f) - mean * mean, 0.f);
    lstat[tid * 2] = mean;
    lstat[tid * 2 + 1] = rsqrtf(var + 1e-5f);
  }
  __syncthreads();

  if constexpr (EPI == 0) {
#pragma unroll
    for (int mi = 0; mi < MI; ++mi) {
#pragma unroll
      for (int j = 0; j < 4; ++j) {
        int row = (mi << 4) + rbase + j;
        float mean = lstat[row * 2], rstd = lstat[row * 2 + 1];
        __hip_bfloat16* hp = Hout + ((size_t)b * (L + 2) + t0 + row + 1) * 256 + cb0;
#pragma unroll
        for (int ni = 0; ni < 4; ++ni) {
          float r = fmaxf(acc[mi][ni][j] + bi[ni], 0.f);
          hp[ni << 4] = __float2bfloat16((r - mean) * rstd * gg[ni] + bb[ni]);
        }
      }
    }
  } else {
    float wlv[4];
#pragma unroll
    for (int ni = 0; ni < 4; ++ni) wlv[ni] = wl[cb0 + (ni << 4)];
#pragma unroll
    for (int mi = 0; mi < MI; ++mi) {
#pragma unroll
      for (int j = 0; j < 4; ++j) {
        int row = (mi << 4) + rbase + j;
        float mean = lstat[row * 2], rstd = lstat[row * 2 + 1];
        float ds = 0.f;
#pragma unroll
        for (int ni = 0; ni < 4; ++ni) {
          float r = fmaxf(acc[mi][ni][j] + bi[ni], 0.f);
          ds += ((r - mean) * rstd * gg[ni] + bb[ni]) * wlv[ni];
        }
#pragma unroll
        for (int d = 1; d < 16; d <<= 1) ds += __shfl_xor(ds, d);
        if ((lane & 15) == 0) lred[row * 8 + wn] = ds;
      }
    }
    __syncthreads();
    if (tid < TM) {
      float z = lred[tid * 8] + lred[tid * 8 + 1] + lred[tid * 8 + 2] + lred[tid * 8 + 3] + blp[0];
      Sout[(size_t)b * L + t0 + tid] = fmaxf(z, 0.f);
    }
  }
}

extern "C" void kernel_launch(void* const* d_in, const int* in_sizes, int n_in,
                              void* d_out, int out_size, void* d_ws, size_t ws_size,
                              hipStream_t stream) {
  const float* x = (const float*)d_in[0];
  const int* dur = (const int*)d_in[1];
  const float* tp = (const float*)d_in[2];
  const float* te = (const float*)d_in[3];
  const float* pq = (const float*)d_in[5];
  const float* eq = (const float*)d_in[6];
  const float* pemb = (const float*)d_in[37];
  const float* eemb = (const float*)d_in[38];

  char* ws = (char*)d_ws;
  __hip_bfloat16* wpb = (__hip_bfloat16*)ws;                 // 6 x 196608 bf16 (fragment-linear)
  __hip_bfloat16* wp[6];
  for (int i = 0; i < 6; ++i) wp[i] = wpb + (size_t)i * 196608;
  __hip_bfloat16* xb = (__hip_bfloat16*)(ws + 2359296);      // [32][258][256]
  __hip_bfloat16* h1dp = (__hip_bfloat16*)(ws + 6586368);    // [32][258][256]
  __hip_bfloat16* M1 = (__hip_bfloat16*)(ws + 10813440);     // [32][2050][256]
  __hip_bfloat16* M2 = (__hip_bfloat16*)(ws + 44400640);     // [32][2050][256]

  float* out = (float*)d_out;

  zero2_kernel<<<256, 256, 0, stream>>>(xb, h1dp, M1, M2);
  packfrag_kernel<<<576, 256, 0, stream>>>((const float*)d_in[7], (const float*)d_in[11],
                                           (const float*)d_in[17], (const float*)d_in[21],
                                           (const float*)d_in[27], (const float*)d_in[31], wpb);
  cvt_pad_kernel<<<2048, 256, 0, stream>>>(x, xb);

  // duration predictor (L=256, TM=64 -> 128 blocks)
  pred_gemm<0, 64><<<128, 256, 0, stream>>>(xb, wp[0], (const float*)d_in[8],
                                            (const float*)d_in[9], (const float*)d_in[10],
                                            nullptr, nullptr, h1dp, nullptr, 256);
  pred_gemm<1, 64><<<128, 256, 0, stream>>>(h1dp, wp[1], (const float*)d_in[12],
                                            (const float*)d_in[13], (const float*)d_in[14],
                                            (const float*)d_in[15], (const float*)d_in[16],
                                            nullptr, out + DUR_OFF, 256);

  // length regulate (true durations) -> M1 bf16; mel_len
  gather_kernel<<<1024, 256, 0, stream>>>(x, dur, M1, out + MEL_OFF);

  // pitch predictor (L=2048): M1 -> M2 -> pitches
  pred_gemm<0, 128><<<512, 256, 0, stream>>>(M1, wp[2], (const float*)d_in[18],
                                             (const float*)d_in[19], (const float*)d_in[20],
                                             nullptr, nullptr, M2, nullptr, 2048);
  pred_gemm<1, 128><<<512, 256, 0, stream>>>(M2, wp[3], (const float*)d_in[22],
                                             (const float*)d_in[23], (const float*)d_in[24],
                                             (const float*)d_in[25], (const float*)d_in[26],
                                             nullptr, out + PIT_OFF, 2048);

  // fused embedding adds: M2 = bf16(M1+pemb), out = M1+pemb+eemb (f32)
  addemb_kernel<<<1024, 256, 0, stream>>>(tp, te, pq, eq, pemb, eemb, M1, M2, out);

  // energy predictor (L=2048): M2 -> M1 -> energies
  pred_gemm<0, 128><<<512, 256, 0, stream>>>(M2, wp[4], (const float*)d_in[28],
                                             (const float*)d_in[29], (const float*)d_in[30],
                                             nullptr, nullptr, M1, nullptr, 2048);
  pred_gemm<1, 128><<<512, 256, 0, stream>>>(M1, wp[5], (const float*)d_in[32],
                                             (const float*)d_in[33], (const float*)d_in[34],
                                             (const float*)d_in[35], (const float*)d_in[36],
                                             nullptr, out + ENE_OFF, 2048);
}

// Round 7
// 348.188 us; speedup vs baseline: 1.3294x; 1.0776x over previous
//
#include <hip/hip_runtime.h>
#include <hip/hip_bf16.h>
#include <stdint.h>

// Problem constants: B=32, T=256, M=2048, C=F=256, K=3 (pad 1), NB=256
#define DUR_OFF 16777216
#define PIT_OFF 16785408
#define ENE_OFF 16850944
#define MEL_OFF 16916480

typedef __attribute__((ext_vector_type(8))) short short8;
typedef __attribute__((ext_vector_type(4))) float f32x4;

__device__ __forceinline__ void async16(const void* g, void* l) {
  __builtin_amdgcn_global_load_lds((__attribute__((address_space(1))) void*)g,
                                   (__attribute__((address_space(3))) void*)l, 16, 0, 0);
}

__device__ __forceinline__ unsigned short bfu(float f) {
  __hip_bfloat16 h = __float2bfloat16(f);
  return __builtin_bit_cast(unsigned short, h);
}
__device__ __forceinline__ float f_from_bf(unsigned short u) {
  return __builtin_bit_cast(float, (unsigned)u << 16);
}

// Zero the two pad rows (t=-1, t=L) of all four padded [B][L+2][256] bf16 buffers.
__global__ void zero2_kernel(__hip_bfloat16* __restrict__ xb, __hip_bfloat16* __restrict__ h1,
                             __hip_bfloat16* __restrict__ M1, __hip_bfloat16* __restrict__ M2) {
  int buf = blockIdx.x >> 6, sub = blockIdx.x & 63;
  int b = sub >> 1, top = sub & 1;
  __hip_bfloat16* p; int L;
  if (buf == 0) { p = xb; L = 256; }
  else if (buf == 1) { p = h1; L = 256; }
  else if (buf == 2) { p = M1; L = 2048; }
  else { p = M2; L = 2048; }
  size_t row = (size_t)b * (L + 2) + (top ? (L + 1) : 0);
  p[row * 256 + threadIdx.x] = __float2bfloat16(0.0f);
}

// Pack all 6 conv weights [F=256][C=256][K=3] f32 (torch OIH) into MFMA-fragment-linear
// bf16 layout: Wfrag[wsel][fb][ni][tap][ks][lane][e], 16 B per (.. lane) chunk, so a wave's
// B-fragment load is base + lane*16 (fully coalesced 1 KB).
//   f = fb*64 + ni*16 + (lane&15);  c = ks*32 + (lane>>4)*8 + e;  kk = tap*256 + c
__global__ void packfrag_kernel(const float* __restrict__ w0, const float* __restrict__ w1,
                                const float* __restrict__ w2, const float* __restrict__ w3,
                                const float* __restrict__ w4, const float* __restrict__ w5,
                                __hip_bfloat16* __restrict__ wpbase) {
  int t = blockIdx.x * 256 + threadIdx.x;   // 147456 total = 6 * 24576 chunks
  int wsel = t / 24576;
  int rem = t % 24576;
  const float* w = wsel == 0 ? w0 : wsel == 1 ? w1 : wsel == 2 ? w2
                 : wsel == 3 ? w3 : wsel == 4 ? w4 : w5;
  __hip_bfloat16* wp = wpbase + (size_t)wsel * 196608;
  int L = rem & 63;
  int ks = (rem >> 6) & 7;
  int q = rem >> 9;            // (fb*4+ni)*3 + tap
  int tap = q % 3, r = q / 3;
  int ni = r & 3, fb = r >> 2;
  int f = fb * 64 + ni * 16 + (L & 15);
  int cb = ks * 32 + ((L >> 4) << 3);
  short8 o;
#pragma unroll
  for (int e = 0; e < 8; ++e)
    o[e] = (short)bfu(w[((size_t)f * 256 + cb + e) * 3 + tap]);
  *(short8*)(wp + (size_t)rem * 8) = o;
}

// x [32][256][256] f32 -> xb [32][258][256] bf16 (row t -> padded row t+1)
__global__ void cvt_pad_kernel(const float* __restrict__ x, __hip_bfloat16* __restrict__ xb) {
  int idx = blockIdx.x * 256 + threadIdx.x;
  float4 v = ((const float4*)x)[idx];
  int c4 = idx & 63;
  int rowi = idx >> 6;
  int b = rowi >> 8, t = rowi & 255;
  ushort4 o;
  o.x = bfu(v.x); o.y = bfu(v.y); o.z = bfu(v.z); o.w = bfu(v.w);
  ((ushort4*)(xb + ((size_t)b * 258 + t + 1) * 256))[c4] = o;
}

// Length regulate (in-block cumsum of true_duration) -> bf16 padded M1; chunk0 writes mel_len.
// Reads bf16 xb (padded) instead of f32 x: same values the predictors see, half the traffic.
__global__ void gather_kernel(const __hip_bfloat16* __restrict__ xb, const int* __restrict__ dur,
                              __hip_bfloat16* __restrict__ outB, float* __restrict__ mel) {
  __shared__ int scs[256];
  __shared__ int sidx[64];
  __shared__ int sval[64];
  int bch = blockIdx.x >> 5;
  int m0 = (blockIdx.x & 31) << 6;
  int tid = threadIdx.x;
  scs[tid] = dur[bch * 256 + tid];
  __syncthreads();
  for (int off = 1; off < 256; off <<= 1) {
    int add = (tid >= off) ? scs[tid - off] : 0;
    __syncthreads();
    scs[tid] += add;
    __syncthreads();
  }
  int total = scs[255];
  if (tid == 0 && (blockIdx.x & 31) == 0)
    mel[bch] = (float)(total < 2048 ? total : 2048);
  if (tid < 64) {
    int m = m0 + tid;
    int lo = 0, hi = 256;
    while (lo < hi) { int mid = (lo + hi) >> 1; if (scs[mid] <= m) lo = mid + 1; else hi = mid; }
    sidx[tid] = lo < 255 ? lo : 255;
    sval[tid] = (m < total);
  }
  __syncthreads();
  int lane = tid & 63, rs = tid >> 6;
  for (int r = rs; r < 64; r += 4) {
    ushort4 o = make_ushort4(0, 0, 0, 0);
    if (sval[r])
      o = ((const ushort4*)(xb + ((size_t)bch * 258 + sidx[r] + 1) * 256))[lane];
    ((ushort4*)(outB + ((size_t)bch * 2050 + m0 + r + 1) * 256))[lane] = o;
  }
}

// Fused double embedding add: M2 = bf16(M1 + pemb[idx_p]); out = (M1 + pemb) + eemb[idx_e] (f32)
__global__ void addemb_kernel(const float* __restrict__ tp, const float* __restrict__ te,
                              const float* __restrict__ pq, const float* __restrict__ eq,
                              const float* __restrict__ pemb, const float* __restrict__ eemb,
                              const __hip_bfloat16* __restrict__ M1, __hip_bfloat16* __restrict__ M2,
                              float* __restrict__ out) {
  __shared__ float sp[255], se[255];
  __shared__ int sip[64], sie[64];
  int bch = blockIdx.x >> 5;
  int m0 = (blockIdx.x & 31) << 6;
  int tid = threadIdx.x;
  if (tid < 255) { sp[tid] = pq[tid]; se[tid] = eq[tid]; }
  __syncthreads();
  if (tid < 64) {
    float xv = tp[bch * 2048 + m0 + tid];
    int lo = 0, hi = 255;
    while (lo < hi) { int mid = (lo + hi) >> 1; if (sp[mid] <= xv) lo = mid + 1; else hi = mid; }
    sip[tid] = lo;
    float ev = te[bch * 2048 + m0 + tid];
    lo = 0; hi = 255;
    while (lo < hi) { int mid = (lo + hi) >> 1; if (se[mid] <= ev) lo = mid + 1; else hi = mid; }
    sie[tid] = lo;
  }
  __syncthreads();
  int lane = tid & 63, rs = tid >> 6;
  for (int r = rs; r < 64; r += 4) {
    ushort4 mv = ((const ushort4*)(M1 + ((size_t)bch * 2050 + m0 + r + 1) * 256))[lane];
    float4 ep = ((const float4*)(pemb + (size_t)sip[r] * 256))[lane];
    float4 ee = ((const float4*)(eemb + (size_t)sie[r] * 256))[lane];
    float4 v;
    v.x = f_from_bf(mv.x) + ep.x; v.y = f_from_bf(mv.y) + ep.y;
    v.z = f_from_bf(mv.z) + ep.z; v.w = f_from_bf(mv.w) + ep.w;
    ushort4 o;
    o.x = bfu(v.x); o.y = bfu(v.y); o.z = bfu(v.z); o.w = bfu(v.w);
    ((ushort4*)(M2 + ((size_t)bch * 2050 + m0 + r + 1) * 256))[lane] = o;
    float4 w;
    w.x = v.x + ee.x; w.y = v.y + ee.y; w.z = v.z + ee.z; w.w = v.w + ee.w;
    ((float4*)(out + ((size_t)bch * 2048 + m0 + r) * 256))[lane] = w;
  }
}

// Load the 4 B fragments of K-slice s (s = tap*8+ks) for this wave's 64-col block.
__device__ __forceinline__ void loadB4(const char* Wb, int s, short8 (&dst)[4]) {
  int tap = s >> 3, ks = s & 7;
#pragma unroll
  for (int ni = 0; ni < 4; ++ni)
    dst[ni] = *(const short8*)(Wb + ((((ni * 3 + tap) << 3) + ks) << 10));
}

// One K-slice of MFMAs: MI swizzled ds_read_b128 for A + MI*4 mfma with the given B buffer.
template <int MI>
__device__ __forceinline__ void sliceMFMA(int s, const char* lA, int rlane, int colp,
                                          const short8 (&bv)[4], f32x4 (&acc)[MI][4]) {
  const int tap = s >> 3, ks = s & 7;
  const int xorv = ((tap + rlane) & 7) << 4;
  short8 av[MI];
#pragma unroll
  for (int mi = 0; mi < MI; ++mi) {
    int a = (tap + (mi << 4) + rlane) * 512 + (ks << 6) + colp;
    av[mi] = *(const short8*)(lA + (a ^ xorv));
  }
#pragma unroll
  for (int mi = 0; mi < MI; ++mi)
#pragma unroll
    for (int ni = 0; ni < 4; ++ni)
      acc[mi][ni] = __builtin_amdgcn_mfma_f32_16x16x32_bf16(av[mi], bv[ni], acc[mi][ni], 0, 0, 0);
}

// Fused conv1d(K=3,'same') + bias + ReLU + LayerNorm GEMM, TM x 256 tile per block
// (4 waves, wave = 64-col block, acc[TM/16][4]).
// A tile ((TM+2) rows x 512 B) staged ONCE via global_load_lds with XOR-swizzled source
// (swz(a) = a ^ (((a>>9)&7)<<4), involution); ONE barrier; then a COMPACT rolled loop of
// 12 iterations x 2 K-slices with named register B-buffers pA/pB (rule-#20 static indexing),
// depth-1 software pipeline: next slice's 4 coalesced 1KB B loads issued before current
// slice's MFMA cluster. Small body keeps I-cache resident and waits counted.
// EPI==0: store LN result bf16 into padded Hout. EPI==1: fold Linear(F->1)+ReLU -> Sout.
template <int EPI, int TM>
__global__ __launch_bounds__(256, 3)
void pred_gemm(const __hip_bfloat16* __restrict__ Ap, const __hip_bfloat16* __restrict__ Wf,
               const float* __restrict__ bias, const float* __restrict__ gamma,
               const float* __restrict__ beta, const float* __restrict__ wl,
               const float* __restrict__ blp, __hip_bfloat16* __restrict__ Hout,
               float* __restrict__ Sout, int L) {
  constexpr int MI = TM / 16;
  constexpr int ABYTES = (TM + 2) * 512;
  __shared__ char lA[ABYTES];
  __shared__ float lred[TM * 8];
  __shared__ float lstat[TM * 2];

  const int tid = threadIdx.x;
  const int wid = tid >> 6;
  const int lane = tid & 63;
  const int wn = wid;              // wave -> 64-col block
  const int tiles = L / TM;
  const int b = blockIdx.x / tiles;
  const int t0 = (blockIdx.x % tiles) * TM;

  // stage A tile: padded rows [t0 .. t0+TM+1] contiguous = ABYTES
  const char* Asrc = (const char*)(Ap + ((size_t)b * (L + 2) + t0) * 256);
#pragma unroll
  for (int j = 0; j < (ABYTES + 4095) / 4096; ++j) {
    int off = j * 4096 + tid * 16;
    if (off < ABYTES) {
      int so = off ^ (((off >> 9) & 7) << 4);
      async16(Asrc + so, lA + off);
    }
  }

  // per-lane fragment-linear weight base for this wave's 64-col block
  const char* Wb = (const char*)Wf + (size_t)wn * 98304 + lane * 16;

  f32x4 acc[MI][4];
  const f32x4 zero4 = {0.f, 0.f, 0.f, 0.f};
#pragma unroll
  for (int i = 0; i < MI; ++i)
#pragma unroll
    for (int j = 0; j < 4; ++j) acc[i][j] = zero4;

  // prefetch slice 0's B fragments; they drain together with the A staging.
  short8 pA[4], pB[4];
  loadB4(Wb, 0, pA);

  __syncthreads();  // waits vmcnt(0): A tile + slice-0 B resident

  const int rlane = lane & 15;
  const int colp = (lane >> 4) << 4;
#pragma unroll 1
  for (int s2 = 0; s2 < 12; ++s2) {
    loadB4(Wb, 2 * s2 + 1, pB);                    // in flight during even slice
    sliceMFMA<MI>(2 * s2, lA, rlane, colp, pA, acc);
    if (s2 < 11) loadB4(Wb, 2 * s2 + 2, pA);       // in flight during odd slice
    sliceMFMA<MI>(2 * s2 + 1, lA, rlane, colp, pB, acc);
  }

  // ---- epilogue: bias + ReLU + LN stats over 256 cols ----
  const int cb0 = (wn << 6) + rlane;
  float bi[4], gg[4], bb[4];
#pragma unroll
  for (int ni = 0; ni < 4; ++ni) {
    int col = cb0 + (ni << 4);
    bi[ni] = bias[col]; gg[ni] = gamma[col]; bb[ni] = beta[col];
  }
  const int rbase = (lane >> 4) << 2;
#pragma unroll
  for (int mi = 0; mi < MI; ++mi) {
#pragma unroll
    for (int j = 0; j < 4; ++j) {
      float s = 0.f, s2 = 0.f;
#pragma unroll
      for (int ni = 0; ni < 4; ++ni) {
        float r = fmaxf(acc[mi][ni][j] + bi[ni], 0.f);
        s += r; s2 += r * r;
      }
#pragma unroll
      for (int d = 1; d < 16; d <<= 1) { s += __shfl_xor(s, d); s2 += __shfl_xor(s2, d); }
      if ((lane & 15) == 0) {
        int row = (mi << 4) + rbase + j;
        lred[row * 8 + wn] = s;
        lred[row * 8 + 4 + wn] = s2;
      }
    }
  }
  __syncthreads();
  if (tid < TM) {
    float s = lred[tid * 8] + lred[tid * 8 + 1] + lred[tid * 8 + 2] + lred[tid * 8 + 3];
    float s2 = lred[tid * 8 + 4] + lred[tid * 8 + 5] + lred[tid * 8 + 6] + lred[tid * 8 + 7];
    float mean = s * (1.f / 256.f);
    float var = fmaxf(s2 * (1.f / 256.f) - mean * mean, 0.f);
    lstat[tid * 2] = mean;
    lstat[tid * 2 + 1] = rsqrtf(var + 1e-5f);
  }
  __syncthreads();

  if constexpr (EPI == 0) {
#pragma unroll
    for (int mi = 0; mi < MI; ++mi) {
#pragma unroll
      for (int j = 0; j < 4; ++j) {
        int row = (mi << 4) + rbase + j;
        float mean = lstat[row * 2], rstd = lstat[row * 2 + 1];
        __hip_bfloat16* hp = Hout + ((size_t)b * (L + 2) + t0 + row + 1) * 256 + cb0;
#pragma unroll
        for (int ni = 0; ni < 4; ++ni) {
          float r = fmaxf(acc[mi][ni][j] + bi[ni], 0.f);
          hp[ni << 4] = __float2bfloat16((r - mean) * rstd * gg[ni] + bb[ni]);
        }
      }
    }
  } else {
    float wlv[4];
#pragma unroll
    for (int ni = 0; ni < 4; ++ni) wlv[ni] = wl[cb0 + (ni << 4)];
#pragma unroll
    for (int mi = 0; mi < MI; ++mi) {
#pragma unroll
      for (int j = 0; j < 4; ++j) {
        int row = (mi << 4) + rbase + j;
        float mean = lstat[row * 2], rstd = lstat[row * 2 + 1];
        float ds = 0.f;
#pragma unroll
        for (int ni = 0; ni < 4; ++ni) {
          float r = fmaxf(acc[mi][ni][j] + bi[ni], 0.f);
          ds += ((r - mean) * rstd * gg[ni] + bb[ni]) * wlv[ni];
        }
#pragma unroll
        for (int d = 1; d < 16; d <<= 1) ds += __shfl_xor(ds, d);
        if ((lane & 15) == 0) lred[row * 8 + wn] = ds;
      }
    }
    __syncthreads();
    if (tid < TM) {
      float z = lred[tid * 8] + lred[tid * 8 + 1] + lred[tid * 8 + 2] + lred[tid * 8 + 3] + blp[0];
      Sout[(size_t)b * L + t0 + tid] = fmaxf(z, 0.f);
    }
  }
}

extern "C" void kernel_launch(void* const* d_in, const int* in_sizes, int n_in,
                              void* d_out, int out_size, void* d_ws, size_t ws_size,
                              hipStream_t stream) {
  const float* x = (const float*)d_in[0];
  const int* dur = (const int*)d_in[1];
  const float* tp = (const float*)d_in[2];
  const float* te = (const float*)d_in[3];
  const float* pq = (const float*)d_in[5];
  const float* eq = (const float*)d_in[6];
  const float* pemb = (const float*)d_in[37];
  const float* eemb = (const float*)d_in[38];

  char* ws = (char*)d_ws;
  __hip_bfloat16* wpb = (__hip_bfloat16*)ws;                 // 6 x 196608 bf16 (fragment-linear)
  __hip_bfloat16* wp[6];
  for (int i = 0; i < 6; ++i) wp[i] = wpb + (size_t)i * 196608;
  __hip_bfloat16* xb = (__hip_bfloat16*)(ws + 2359296);      // [32][258][256]
  __hip_bfloat16* h1dp = (__hip_bfloat16*)(ws + 6586368);    // [32][258][256]
  __hip_bfloat16* M1 = (__hip_bfloat16*)(ws + 10813440);     // [32][2050][256]
  __hip_bfloat16* M2 = (__hip_bfloat16*)(ws + 44400640);     // [32][2050][256]

  float* out = (float*)d_out;

  zero2_kernel<<<256, 256, 0, stream>>>(xb, h1dp, M1, M2);
  packfrag_kernel<<<576, 256, 0, stream>>>((const float*)d_in[7], (const float*)d_in[11],
                                           (const float*)d_in[17], (const float*)d_in[21],
                                           (const float*)d_in[27], (const float*)d_in[31], wpb);
  cvt_pad_kernel<<<2048, 256, 0, stream>>>(x, xb);

  // duration predictor (L=256, TM=32 -> 256 blocks: every CU busy)
  pred_gemm<0, 32><<<256, 256, 0, stream>>>(xb, wp[0], (const float*)d_in[8],
                                            (const float*)d_in[9], (const float*)d_in[10],
                                            nullptr, nullptr, h1dp, nullptr, 256);
  pred_gemm<1, 32><<<256, 256, 0, stream>>>(h1dp, wp[1], (const float*)d_in[12],
                                            (const float*)d_in[13], (const float*)d_in[14],
                                            (const float*)d_in[15], (const float*)d_in[16],
                                            nullptr, out + DUR_OFF, 256);

  // length regulate (true durations) -> M1 bf16; mel_len
  gather_kernel<<<1024, 256, 0, stream>>>(xb, dur, M1, out + MEL_OFF);

  // pitch predictor (L=2048, TM=64 -> 1024 blocks): M1 -> M2 -> pitches
  pred_gemm<0, 64><<<1024, 256, 0, stream>>>(M1, wp[2], (const float*)d_in[18],
                                             (const float*)d_in[19], (const float*)d_in[20],
                                             nullptr, nullptr, M2, nullptr, 2048);
  pred_gemm<1, 64><<<1024, 256, 0, stream>>>(M2, wp[3], (const float*)d_in[22],
                                             (const float*)d_in[23], (const float*)d_in[24],
                                             (const float*)d_in[25], (const float*)d_in[26],
                                             nullptr, out + PIT_OFF, 2048);

  // fused embedding adds: M2 = bf16(M1+pemb), out = M1+pemb+eemb (f32)
  addemb_kernel<<<1024, 256, 0, stream>>>(tp, te, pq, eq, pemb, eemb, M1, M2, out);

  // energy predictor (L=2048): M2 -> M1 -> energies
  pred_gemm<0, 64><<<1024, 256, 0, stream>>>(M2, wp[4], (const float*)d_in[28],
                                             (const float*)d_in[29], (const float*)d_in[30],
                                             nullptr, nullptr, M1, nullptr, 2048);
  pred_gemm<1, 64><<<1024, 256, 0, stream>>>(M1, wp[5], (const float*)d_in[32],
                                             (const float*)d_in[33], (const float*)d_in[34],
                                             (const float*)d_in[35], (const float*)d_in[36],
                                             nullptr, out + ENE_OFF, 2048);
}